// Round 9
// baseline (147.934 us; speedup 1.0000x reference)
//
#include <hip/hip_runtime.h>
#include <hip/hip_bf16.h>
#include <math.h>

#define BATCH 16
#define NPTS 1024
#define DIM 64
#define EPSF 0.1f
#define INV_EPS 10.0f
#define MAX_ITER 100
#define THRESHF 0.1f
#define LSTRIDE 72  // shorts; 64+8 pad keeps b128 LDS reads conflict-cheap

typedef _Float16 h8 __attribute__((ext_vector_type(8)));
typedef _Float16 half2v __attribute__((ext_vector_type(2)));
typedef short short8v __attribute__((ext_vector_type(8)));
typedef float float4v __attribute__((ext_vector_type(4)));

// extract packed half pair P (template => parse-time constant indices)
template <int P>
__device__ __forceinline__ half2v h2get(h8 v) {
  return __builtin_shufflevector(v, v, 2 * P, 2 * P + 1);
}

#define ATOMIC_ST(p, v) \
  __hip_atomic_store((p), (v), __ATOMIC_RELAXED, __HIP_MEMORY_SCOPE_AGENT)
#define ATOMIC_LD(p) \
  __hip_atomic_load((p), __ATOMIC_RELAXED, __HIP_MEMORY_SCOPE_AGENT)

__device__ inline float waveSum(float x) {
#pragma unroll
  for (int off = 32; off; off >>= 1) x += __shfl_xor(x, off, 64);
  return x;
}
__device__ inline float waveMax(float x) {
#pragma unroll
  for (int off = 32; off; off >>= 1) x = fmaxf(x, __shfl_xor(x, off, 64));
  return x;
}

// Group barrier (8 waves), LDS generation counter. GBAR_L orders LDS only
// (lgkmcnt) -> global prefetch loads stay in flight across it (better than
// __syncthreads' full drain). GBAR_V additionally drains vmcnt -> used where
// round-8 relied on __syncthreads' "atomics acked at L3" semantics.
// Relaxed add + acquire spin: producer-side ordering via the explicit
// s_waitcnt (asm memory-clobber = compiler fence; waitcnt completes the
// ds/global ops before the arrive is issued).
#define GBAR_IMPL(WAITSTR)                                                  \
  do {                                                                      \
    gen += 8;                                                               \
    asm volatile(WAITSTR ::: "memory");                                     \
    if (lane == 0)                                                          \
      __hip_atomic_fetch_add(&bar[grp], 1, __ATOMIC_RELAXED,                \
                             __HIP_MEMORY_SCOPE_WORKGROUP);                 \
    while (__hip_atomic_load(&bar[grp], __ATOMIC_ACQUIRE,                   \
                             __HIP_MEMORY_SCOPE_WORKGROUP) < gen)           \
      __builtin_amdgcn_s_sleep(1);                                         \
  } while (0)
#define GBAR_L() GBAR_IMPL("s_waitcnt lgkmcnt(0)")
#define GBAR_V() GBAR_IMPL("s_waitcnt vmcnt(0) lgkmcnt(0)")

// Round-9: two-group co-residency for TLP. 128 blocks x 1024 threads,
// 1 block/CU = 16 waves/CU (4/SIMD). Each block hosts TWO groups of 8
// waves; group = exactly one round-8 block: slab sid = blk*2+grp,
// batch=(sid&7)+8*(sid>>7), kslot=(sid>>3)&15 -> groups in a block serve
// DIFFERENT batches, so their exchange gates are independent: when group
// A's waves block on the L3 poll (vmcnt stall, no issue pressure), group
// B's waves issue VALU on the same SIMDs. Protocol per group is round-8
// verbatim (16 writers/batch staggered f32 atomicAdd colsum[3], 64-bit
// flags tag<<32|delta, lag-1 errB stop). Intra-group sync = LDS-counter
// barriers above. colpart stored fp16 (bit-exact: values are already
// fp16-rounded) to fit 2 working sets in ~138KB LDS.
// Poison-compat (0xAA): flag tag high-word signed (poison < 1), errB "<0"
// sentinel, costPart +1.0 bias "<0.5" sentinel, colsum zeroed in prologue,
// bar/LDS initialized before use. Cross-block data via relaxed agent-scope
// ops (L3 coherence point); ordering = per-wave vmcnt drain + group
// barrier + monotonic flags. Early stop is global (same errB sum in every
// group) -> both groups exit at the same iteration; the block-wide
// __syncthreads in the epilogue is therefore reached by all 16 waves.
__global__ __launch_bounds__(1024, 4) void sinkhorn_fused(
    const float* __restrict__ x, const float* __restrict__ y,
    __hip_bfloat16* __restrict__ syh,  // [BATCH*NPTS*DIM] bf16
    float* __restrict__ y2,            // [BATCH*NPTS]
    float* __restrict__ colsum,        // [3][BATCH][NPTS] (scaled x1024)
    long long* __restrict__ flags,     // [BATCH][16]: tag<<32 | delta bits
    float* __restrict__ errB,          // [MAX_ITER][BATCH], sentinel <0
    float* __restrict__ costPart,      // [128], sentinel <0.5
    float* __restrict__ out) {
  __shared__ __attribute__((aligned(16))) short xs[2][64 * LSTRIDE];
  __shared__ __attribute__((aligned(16))) short ys[2][2][64 * LSTRIDE];
  __shared__ __attribute__((aligned(16))) short os[2][2][64 * LSTRIDE];
  __shared__ __attribute__((aligned(16))) float wLDS[2][NPTS];
  __shared__ __attribute__((aligned(16))) _Float16 whL[2][NPTS];
  __shared__ __attribute__((aligned(16))) _Float16 colpartH[2][8][NPTS];
  __shared__ float x2L[2][64];
  __shared__ float derrG[2][8];
  __shared__ float errbL[2][BATCH];
  __shared__ int bar[2];
  const int t = threadIdx.x;
  const int grp = t >> 9;        // group 0/1
  const int gt = t & 511;        // group-local tid
  const int wave = gt >> 6;      // 0..7 within group
  const int lane = t & 63;
  const int sid = blockIdx.x * 2 + grp;  // slab id 0..255
  const int batch = (sid & 7) + 8 * (sid >> 7);
  const int kslot = (sid >> 3) & 15;
  const float log_mu = logf(1.0f / 1024.0f + 1e-8f);
  const float mu_c = 1.0f / 1024.0f + 1e-8f;  // exp(log_mu)

  if (t < 2) bar[t] = 0;
  __syncthreads();  // bar initialized before any group barrier
  int gen = 0;

  // ---- Phase 0: softmax. x-rows -> LDS only; y-rows -> global via L3. ----
#pragma unroll
  for (int rr = 0; rr < 8; rr++) {
    int rl = wave * 8 + rr;  // 0..63 local row
    int gr = batch * NPTS + kslot * 64 + rl;
    // x row (consumed only by this group: keep in LDS)
    float xv = x[(size_t)gr * DIM + lane];
    float mx = waveMax(xv);
    float ex = __expf(xv - mx);
    float sx = waveSum(ex);
    float px = ex / sx;
    __hip_bfloat16 hbx = (__hip_bfloat16)px;
    xs[grp][rl * LSTRIDE + lane] = *(const short*)&hbx;
    float sqx = waveSum(px * px);
    if (lane == 0) x2L[grp][rl] = sqx;
    // y row (consumed by whole batch: publish write-through to L3)
    float yv = y[(size_t)gr * DIM + lane];
    float my = waveMax(yv);
    float ey = __expf(yv - my);
    float sy = waveSum(ey);
    float py = ey / sy;
    __hip_bfloat16 hby = (__hip_bfloat16)py;
    unsigned bits = *(const unsigned short*)&hby;
    unsigned nb = __shfl_down(bits, 1);
    if ((lane & 1) == 0)
      ATOMIC_ST((unsigned*)((unsigned short*)syh + (size_t)gr * DIM + lane),
                bits | (nb << 16));
    float sqy = waveSum(py * py);
    if (lane == 0) ATOMIC_ST(&y2[gr], sqy);
  }
  // zero own colsum slices of all 3 buffers (before any peer can add)
  if (gt < 192) {
    int buf = gt >> 6, j = kslot * 64 + (gt & 63);
    ATOMIC_ST(&colsum[((size_t)buf * BATCH + batch) * NPTS + j], 0.f);
  }
  GBAR_V();  // all waves' publishes/zeros acked at L3 before leader flags
  if (gt == 0) ATOMIC_ST(&flags[batch * 16 + kslot], (long long)1 << 32);
  if (gt < 16) {
    while ((int)(ATOMIC_LD(&flags[batch * 16 + gt]) >> 32) < 1) {}
  }
  GBAR_L();

  // ---- Prologue: build K slab (64x1024, packed fp16) via MFMA ----
  // T14 async-stage: prefetch step k+1's 16KB into regs before step k's
  // MFMA/expf; ds_write after the barrier. GBAR_L doesn't drain vmcnt ->
  // the prefetch loads now genuinely span the barrier.
  const int m = lane & 15, q = lane >> 4;
  const int g = lane >> 3, sub = lane & 7;
  const int sw = wave & 3, ts = wave >> 2;
  short8v a0 = *(const short8v*)&xs[grp][(sw * 16 + m) * LSTRIDE + q * 8];
  short8v a1 = *(const short8v*)&xs[grp][(sw * 16 + m) * LSTRIDE + 32 + q * 8];
  float xa[4];
#pragma unroll
  for (int reg = 0; reg < 4; reg++) xa[reg] = x2L[grp][sw * 16 + q * 4 + reg];
  h8 ka[8], kb[8];  // K row-slab: cols [8*lane,+8) and [512+8*lane,+8)
  {
    const int r0 = gt >> 3, c0 = (gt & 7) * 8;
    const int r1 = (gt + 512) >> 3, c1 = ((gt + 512) & 7) * 8;
    const short* syb = (const short*)syh + (size_t)batch * NPTS * DIM;
    short8v pf0 = *(const short8v*)(syb + (size_t)r0 * DIM + c0);
    short8v pf1 = *(const short8v*)(syb + (size_t)r1 * DIM + c1);
    *(short8v*)&ys[grp][r0 >> 6][(r0 & 63) * LSTRIDE + c0] = pf0;
    *(short8v*)&ys[grp][r1 >> 6][(r1 & 63) * LSTRIDE + c1] = pf1;
    GBAR_L();  // stage 0 visible
#pragma unroll
    for (int k = 0; k < 8; k++) {
      if (k < 7) {  // issue next-stage loads; flight hides under MFMA+expf
        pf0 = *(const short8v*)(syb + (size_t)(128 * (k + 1) + r0) * DIM + c0);
        pf1 = *(const short8v*)(syb + (size_t)(128 * (k + 1) + r1) * DIM + c1);
      }
      const int jt = 2 * k + ts;
      float4v accv[4];
#pragma unroll
      for (int tj = 0; tj < 4; tj++) {
        short8v b0 = *(const short8v*)&ys[grp][ts][(tj * 16 + m) * LSTRIDE + q * 8];
        short8v b1 = *(const short8v*)&ys[grp][ts][(tj * 16 + m) * LSTRIDE + 32 + q * 8];
        float4v c = {0.f, 0.f, 0.f, 0.f};
        c = __builtin_amdgcn_mfma_f32_16x16x32_bf16(a0, b0, c, 0, 0, 0);
        c = __builtin_amdgcn_mfma_f32_16x16x32_bf16(a1, b1, c, 0, 0, 0);
        accv[tj] = c;
      }
#pragma unroll
      for (int tj = 0; tj < 4; tj++) {
        float y2v = y2[(size_t)batch * NPTS + jt * 64 + tj * 16 + m];
#pragma unroll
        for (int reg = 0; reg < 4; reg++) {
          float C = xa[reg] + y2v - 2.0f * accv[tj][reg];
          _Float16 kv = (_Float16)__expf(-INV_EPS * C);
          os[grp][ts][(sw * 16 + q * 4 + reg) * LSTRIDE + tj * 16 + m] =
              *(const short*)&kv;
        }
      }
      GBAR_L();  // os visible; ys(k) fully consumed
      {
        int e0 = (2 * k) & 7, e1 = (2 * k + 1) & 7;
        if (g == e0 || g == e1) {
          const short* srcp = (g == e0) ? &os[grp][0][0] : &os[grp][1][0];
#pragma unroll
          for (int rr = 0; rr < 8; rr++) {
            h8 v = *(const h8*)&srcp[(wave * 8 + rr) * LSTRIDE + sub * 8];
            if (k < 4) ka[rr] = v; else kb[rr] = v;
          }
        }
      }
      if (k < 7) {  // ys(k) consumed above the barrier -> safe to overwrite
        *(short8v*)&ys[grp][r0 >> 6][(r0 & 63) * LSTRIDE + c0] = pf0;
        *(short8v*)&ys[grp][r1 >> 6][(r1 & 63) * LSTRIDE + c1] = pf1;
      }
      GBAR_L();  // ys(k+1) visible; os consumed before next overwrite
    }
  }

  for (int j = gt; j < NPTS; j += 512) {
    wLDS[grp][j] = 1.f;
    whL[grp][j] = (_Float16)1.f;
  }
  GBAR_L();

  float eu[8], euPrev[8];  // eu = exp(u/eps); u never materialized
#pragma unroll
  for (int r = 0; r < 8; r++) eu[r] = 1.f;
  int it = 0;

  while (true) {
#pragma unroll
    for (int r = 0; r < 8; r++) euPrev[r] = eu[r];
    // ---- Phase A: u update + column partials (packed fp16) ----
    h8 wh0 = *(const h8*)&whL[grp][8 * lane];        // cols [8*lane, +8)
    h8 wh1 = *(const h8*)&whL[grp][512 + 8 * lane];  // cols [512+8*lane, +8)
    half2v c0[4], c1[4];  // scaled column partials (x1024), fp16
#pragma unroll
    for (int p = 0; p < 4; p++) {
      c0[p] = half2v{(_Float16)0.f, (_Float16)0.f};
      c1[p] = half2v{(_Float16)0.f, (_Float16)0.f};
    }
    float delta = 0.f;
#pragma unroll
    for (int rr = 0; rr < 8; rr++) {
      float d0 = 0.f, d1 = 0.f;
#define DOT_STEP(P)                                                         \
  d0 = __builtin_amdgcn_fdot2(h2get<P>(ka[rr]), h2get<P>(wh0), d0, false);  \
  d1 = __builtin_amdgcn_fdot2(h2get<P>(kb[rr]), h2get<P>(wh1), d1, false);
      DOT_STEP(0) DOT_STEP(1) DOT_STEP(2) DOT_STEP(3)
#undef DOT_STEP
      float dot = waveSum(d0 + d1);
      float sp = eu[rr] * dot + 1e-6f;
      float lg = __logf(sp);
      delta += fabsf(EPSF * (log_mu - lg));  // == |u_new - u_old|
      float ai = mu_c * eu[rr] * __builtin_amdgcn_rcpf(sp);  // exp(u_new/eps)
      eu[rr] = ai;
      _Float16 aih = (_Float16)(ai * 1024.0f);  // scaled: keeps fp16 normal
      half2v ai2 = {aih, aih};
#define FMA_STEP(P)                                 \
  c0[P] = h2get<P>(ka[rr]) * ai2 + c0[P];           \
  c1[P] = h2get<P>(kb[rr]) * ai2 + c1[P];
      FMA_STEP(0) FMA_STEP(1) FMA_STEP(2) FMA_STEP(3)
#undef FMA_STEP
    }
    if (lane == 0) derrG[grp][wave] = delta;
    {
      // store partials fp16 (bit-exact: c0/c1 are already fp16 values)
      _Float16* cph = &colpartH[grp][wave][0];
#pragma unroll
      for (int p = 0; p < 4; p++) {
        *(half2v*)&cph[8 * lane + 2 * p] = c0[p];
        *(half2v*)&cph[512 + 8 * lane + 2 * p] = c1[p];
      }
    }
    GBAR_L();  // S1: colpartH + derr visible
    // block partial -> f32 atomicAdd into L3 colsum, STAGGERED by kslot so
    // concurrent slabs' bursts hit disjoint cache lines.
    float* cs = colsum + ((size_t)(it % 3) * BATCH + batch) * NPTS;
    {
      int j0 = (gt + (kslot << 6)) & 1023;
      int j1 = j0 ^ 512;
      float s0 = 0.f, s1 = 0.f;
#pragma unroll
      for (int w = 0; w < 8; w++) {
        s0 += (float)colpartH[grp][w][j0];
        s1 += (float)colpartH[grp][w][j1];
      }
      unsafeAtomicAdd(&cs[j0], s0);
      unsafeAtomicAdd(&cs[j1], s1);
    }
    // pre-drain window: lag-1 errB retry overlaps the atomic ack
    if (it >= 1 && gt < BATCH) {
      float v;
      while ((v = ATOMIC_LD(&errB[(it - 1) * BATCH + gt])) < 0.f) {}
      errbL[grp][gt] = v;
    }
    float eblk = 0.f;
    if (gt == 0) {
#pragma unroll
      for (int w = 0; w < 8; w++) eblk += derrG[grp][w];
    }
    GBAR_V();  // S2: all waves' atomics acked at L3 + errbL visible
    if (gt == 0)
      ATOMIC_ST(&flags[batch * 16 + kslot],
                ((long long)(it + 2) << 32) | (long long)__float_as_uint(eblk));
    // ---- lag-1 global stop check (same errB data in every group ->
    // all groups exit at the same iteration) ----
    if (it >= 1) {
      float errv = 0.f;
#pragma unroll
      for (int k = 0; k < BATCH; k++) errv += errbL[grp][k];
      if (errv * (1.0f / (float)BATCH) < THRESHF) {
        // reference stopped after body it-1: undo this iteration's u update
#pragma unroll
        for (int r = 0; r < 8; r++) eu[r] = euPrev[r];
        break;
      }
    }
    // poll peers' flags; the same word carries their deltas
    float dpoll = 0.f;
    if (gt < 16) {
      long long fw;
      while ((int)((fw = ATOMIC_LD(&flags[batch * 16 + gt])) >> 32) < it + 2) {}
      dpoll = __uint_as_float((unsigned)fw);
    }
    GBAR_L();  // S3: all threads past poll
    // column-sum loads first (critical path; values final per flags)
    float cs0 = ATOMIC_LD(&cs[gt]);
    float cs1 = ATOMIC_LD(&cs[gt + 512]);
    // zero the buffer for iteration it+2 (race-free: peers' it-1 reads done
    // before they flagged it+2; first adds to it occur after it+2's poll)
    if (gt < 64)
      ATOMIC_ST(&colsum[((size_t)((it + 2) % 3) * BATCH + batch) * NPTS +
                        kslot * 64 + gt], 0.f);
    // batch err for iteration it: shfl-reduce the 16 polled deltas (group
    // wave 0); kslot==0 leader publishes for the cross-batch lag-1 check.
    if (wave == 0) {
      float e16 = (lane < 16) ? dpoll : 0.f;
#pragma unroll
      for (int off = 8; off; off >>= 1) e16 += __shfl_xor(e16, off, 16);
      if (gt == 0 && kslot == 0) ATOMIC_ST(&errB[it * BATCH + batch], e16);
    }
    // ---- Phase B: w update, multiplicative, 1024-scale folded bit-exactly:
    // mu*w*rcp(w*cs' + 1e-6*1024)*1024 == mu*w*rcp(w*(cs'/1024) + 1e-6) ----
    {
      float w0 = wLDS[grp][gt];
      float wn0 = mu_c * w0 *
                  __builtin_amdgcn_rcpf(w0 * cs0 + (1e-6f * 1024.0f)) * 1024.0f;
      wLDS[grp][gt] = wn0;
      whL[grp][gt] = (_Float16)wn0;
      float w1 = wLDS[grp][gt + 512];
      float wn1 = mu_c * w1 *
                  __builtin_amdgcn_rcpf(w1 * cs1 + (1e-6f * 1024.0f)) * 1024.0f;
      wLDS[grp][gt + 512] = wn1;
      whL[grp][gt + 512] = (_Float16)wn1;
    }
    it++;
    if (it >= MAX_ITER) break;
    GBAR_L();  // S4: wLDS/whL writes visible before next phase A reads
  }

  // ---- Final cost: pi = a_i*K*w_j, C = -eps*log(K) ----
  {
    GBAR_L();  // group's last wLDS writes visible
    const float4* w4 = (const float4*)&wLDS[grp][0];
    float wreg[16];
    *(float4*)&wreg[0]  = w4[2 * lane];
    *(float4*)&wreg[4]  = w4[2 * lane + 1];
    *(float4*)&wreg[8]  = w4[128 + 2 * lane];
    *(float4*)&wreg[12] = w4[128 + 2 * lane + 1];
    float csum = 0.f;
#pragma unroll
    for (int rr = 0; rr < 8; rr++) {
      float ai = eu[rr];  // == exp(u/eps)
#pragma unroll
      for (int n = 0; n < 8; n++) {
        float kf = (float)ka[rr][n];
        if (kf > 0.f)
          csum += ai * wreg[n] * kf * (-EPSF * __logf(kf));
        float kg = (float)kb[rr][n];
        if (kg > 0.f)
          csum += ai * wreg[8 + n] * kg * (-EPSF * __logf(kg));
      }
    }
    csum = waveSum(csum);
    if (lane == 0) derrG[grp][wave] = csum;
    __syncthreads();  // block-wide: both groups exited at the same iteration
    if (t == 0) {
      float cst = 0.f;
#pragma unroll
      for (int w = 0; w < 8; w++) cst += derrG[0][w] + derrG[1][w];
      ATOMIC_ST(&costPart[blockIdx.x], cst + 1.0f);  // sentinel-safe bias
    }
    // block 0 gathers all 128 partials and writes the scalar output
    if (blockIdx.x == 0) {
      float* gb = (float*)&colpartH[0][0][0];
      if (t < 128) {
        float v;
        while ((v = ATOMIC_LD(&costPart[t])) < 0.5f) {}
        gb[t] = v;
      }
      __syncthreads();
      if (t < 64) {
        float s = gb[lane] + gb[lane + 64];
        s = waveSum(s);
        if (lane == 0) out[0] = (s - 128.0f) * (1.0f / (float)BATCH);
      }
    }
  }
}

extern "C" void kernel_launch(void* const* d_in, const int* in_sizes, int n_in,
                              void* d_out, int out_size, void* d_ws,
                              size_t ws_size, hipStream_t stream) {
  (void)in_sizes; (void)n_in; (void)out_size; (void)ws_size;
  const float* x = (const float*)d_in[0];
  const float* y = (const float*)d_in[1];
  float* out = (float*)d_out;

  char* ws = (char*)d_ws;
  size_t off = 0;
  auto alloc = [&](size_t nbytes) -> void* {
    void* p = (void*)(ws + off);
    off = (off + nbytes + 255) & ~(size_t)255;
    return p;
  };
  __hip_bfloat16* syh = (__hip_bfloat16*)alloc((size_t)BATCH * NPTS * DIM * 2);
  float* y2 = (float*)alloc((size_t)BATCH * NPTS * 4);
  float* colsum = (float*)alloc((size_t)3 * BATCH * NPTS * 4);
  long long* flags = (long long*)alloc((size_t)BATCH * 16 * 8);
  float* errB = (float*)alloc((size_t)MAX_ITER * BATCH * 4);
  float* costPart = (float*)alloc(256 * 4);

  void* args[] = {&x, &y, &syh, &y2, &colsum, &flags,
                  &errB, &costPart, &out};
  hipLaunchCooperativeKernel((void*)sinkhorn_fused, dim3(128), dim3(1024),
                             args, 0, stream);
}

// Round 11
// 142.657 us; speedup vs baseline: 1.0370x; 1.0370x over previous
//
#include <hip/hip_runtime.h>
#include <hip/hip_bf16.h>
#include <math.h>

#define BATCH 16
#define NPTS 1024
#define DIM 64
#define EPSF 0.1f
#define INV_EPS 10.0f
#define MAX_ITER 100
#define THRESHF 0.1f
#define LSTRIDE 72  // shorts; 64+8 pad keeps b128 LDS reads conflict-cheap

typedef _Float16 h8 __attribute__((ext_vector_type(8)));
typedef short short8v __attribute__((ext_vector_type(8)));
typedef float float4v __attribute__((ext_vector_type(4)));

#define ATOMIC_ST(p, v) \
  __hip_atomic_store((p), (v), __ATOMIC_RELAXED, __HIP_MEMORY_SCOPE_AGENT)
#define ATOMIC_LD(p) \
  __hip_atomic_load((p), __ATOMIC_RELAXED, __HIP_MEMORY_SCOPE_AGENT)

__device__ inline float waveSum(float x) {
#pragma unroll
  for (int off = 32; off; off >>= 1) x += __shfl_xor(x, off, 64);
  return x;
}
__device__ inline float waveMax(float x) {
#pragma unroll
  for (int off = 32; off; off >>= 1) x = fmaxf(x, __shfl_xor(x, off, 64));
  return x;
}

// Single fused cooperative kernel. 256 blocks x 512 threads, 1 block/CU.
// Block owns rows [kslot*64,+64) of batch (blk&7)+8*(blk>>7).
//
// Round-11 = round-10 resubmit (infra failure) with the colsum-address bug
// fixed: partials are now added at cs[col] (value/address matched, as in
// round 8); burst-stagger comes from rotating the tl issue order by kslot
// instead of offsetting the address.
//
// Round-8 exchange protocol (best measured, bit-identical) with Phase A
// moved onto MFMA (vector-pipe matvecs were 29% VALUBusy, MfmaUtil 1.4%):
//  - K resident TWICE per wave, in the two mfma operand layouts (layouts
//    are the ones this kernel's own verified prologue uses):
//      kA[16]: A-layout, rows [sw*16,+16) x cols [ts*512,+512)
//              (sw=wave&3, ts=wave>>2; lane m=lane&15 row, q=lane>>4 k-grp)
//      kB[16]: B-layout, all 64 rows x cols [wave*128,+128)
//  - row dots: 16 mfma_f32_16x16x32_f16(kA[s], w-frag bcast) -> C[reg] =
//    dot(row sw*16+q*4+reg) dup over m; m==0 lanes -> dotL.
//  - u-update: threads t<64 (1 row each), eu in LDS (euL), a*1024 -> ahF
//    fp16 (same x1024 scaling as rounds 5/8, folds bit-exactly in Phase B).
//  - colparts: mfma(a-frag bcast, kB) -> C[0] = colpart(col) dup; q==0
//    lanes issue the f32 atomicAdds directly (tl order rotated by kslot).
//    The colpart LDS exchange (32KB + its barrier traffic) is deleted.
// Exchange: staggered atomicAdd colsum[3] triple-buffer, 64-bit flags
// tag<<32|delta, lag-1 errB stop — unchanged from round 8.
// Poison-compat (0xAA): flag tag high-word signed (poison<1), errB "<0"
// sentinel, costPart +1.0 bias "<0.5" sentinel, colsum zeroed in prologue.
__global__ __launch_bounds__(512, 2) void sinkhorn_fused(
    const float* __restrict__ x, const float* __restrict__ y,
    __hip_bfloat16* __restrict__ syh,  // [BATCH*NPTS*DIM] bf16
    float* __restrict__ y2,            // [BATCH*NPTS]
    float* __restrict__ colsum,        // [3][BATCH][NPTS] (scaled x1024)
    long long* __restrict__ flags,     // [BATCH][16]: tag<<32 | delta bits
    float* __restrict__ errB,          // [MAX_ITER][BATCH], sentinel <0
    float* __restrict__ costPart,      // [256], sentinel <0.5
    float* __restrict__ out) {
  __shared__ __attribute__((aligned(16))) short xs[64 * LSTRIDE];
  __shared__ __attribute__((aligned(16))) short ys[2][64 * LSTRIDE];
  __shared__ __attribute__((aligned(16))) short os[2][64 * LSTRIDE];
  __shared__ __attribute__((aligned(16))) float wLDS[NPTS];
  __shared__ __attribute__((aligned(16))) _Float16 whL[NPTS];
  __shared__ __attribute__((aligned(16))) _Float16 ahF[64];  // a*1024 fp16
  __shared__ __attribute__((aligned(16))) float dotL[2][64];
  __shared__ __attribute__((aligned(16))) float euL[64];
  __shared__ float x2L[64];
  __shared__ float derr[8];
  __shared__ float errbL[BATCH];
  const int t = threadIdx.x;
  const int blk = blockIdx.x;
  const int wave = t >> 6, lane = t & 63;
  const int batch = (blk & 7) + 8 * (blk >> 7);
  const int kslot = (blk >> 3) & 15;
  const float log_mu = logf(1.0f / 1024.0f + 1e-8f);
  const float mu_c = 1.0f / 1024.0f + 1e-8f;  // exp(log_mu)

  // ---- Phase 0: softmax. x-rows -> LDS only; y-rows -> global via L3. ----
#pragma unroll
  for (int rr = 0; rr < 8; rr++) {
    int rl = wave * 8 + rr;  // 0..63 local row
    int gr = batch * NPTS + kslot * 64 + rl;
    float xv = x[(size_t)gr * DIM + lane];
    float mx = waveMax(xv);
    float ex = __expf(xv - mx);
    float sx = waveSum(ex);
    float px = ex / sx;
    __hip_bfloat16 hbx = (__hip_bfloat16)px;
    xs[rl * LSTRIDE + lane] = *(const short*)&hbx;
    float sqx = waveSum(px * px);
    if (lane == 0) x2L[rl] = sqx;
    float yv = y[(size_t)gr * DIM + lane];
    float my = waveMax(yv);
    float ey = __expf(yv - my);
    float sy = waveSum(ey);
    float py = ey / sy;
    __hip_bfloat16 hby = (__hip_bfloat16)py;
    unsigned bits = *(const unsigned short*)&hby;
    unsigned nb = __shfl_down(bits, 1);
    if ((lane & 1) == 0)
      ATOMIC_ST((unsigned*)((unsigned short*)syh + (size_t)gr * DIM + lane),
                bits | (nb << 16));
    float sqy = waveSum(py * py);
    if (lane == 0) ATOMIC_ST(&y2[gr], sqy);
  }
  // zero own colsum slices of all 3 buffers (before any peer can add)
  if (t < 192) {
    int buf = t >> 6, j = kslot * 64 + (t & 63);
    ATOMIC_ST(&colsum[((size_t)buf * BATCH + batch) * NPTS + j], 0.f);
  }
  __syncthreads();  // vmcnt drain: all publishes complete at L3
  if (t == 0) ATOMIC_ST(&flags[batch * 16 + kslot], (long long)1 << 32);
  if (t < 16) {
    while ((int)(ATOMIC_LD(&flags[batch * 16 + t]) >> 32) < 1) {}
  }
  __syncthreads();

  // ---- Prologue: build K slab via MFMA; grab kA (A-layout) + kB (B-layout)
  // from the os tiles. T14 prefetch of next stage spans the compute. ----
  const int m = lane & 15, q = lane >> 4;
  const int sw = wave & 3, ts = wave >> 2;
  short8v a0 = *(const short8v*)&xs[(sw * 16 + m) * LSTRIDE + q * 8];
  short8v a1 = *(const short8v*)&xs[(sw * 16 + m) * LSTRIDE + 32 + q * 8];
  float xa[4];
#pragma unroll
  for (int reg = 0; reg < 4; reg++) xa[reg] = x2L[sw * 16 + q * 4 + reg];
  h8 kA[16];  // rows [sw*16,+16) x cols [ts*512,+512): frag s -> cols s*32
  h8 kB[16];  // all 64 rows x cols [wave*128,+128): frag 2*tl+h
  {
    const int r0 = t >> 3, c0 = (t & 7) * 8;
    const int r1 = (t + 512) >> 3, c1 = ((t + 512) & 7) * 8;
    const short* syb = (const short*)syh + (size_t)batch * NPTS * DIM;
    short8v pf0 = *(const short8v*)(syb + (size_t)r0 * DIM + c0);
    short8v pf1 = *(const short8v*)(syb + (size_t)r1 * DIM + c1);
    *(short8v*)&ys[r0 >> 6][(r0 & 63) * LSTRIDE + c0] = pf0;
    *(short8v*)&ys[r1 >> 6][(r1 & 63) * LSTRIDE + c1] = pf1;
    __syncthreads();  // stage 0 visible
#pragma unroll
    for (int k = 0; k < 8; k++) {
      if (k < 7) {  // issue next-stage loads; flight hides under MFMA+expf
        pf0 = *(const short8v*)(syb + (size_t)(128 * (k + 1) + r0) * DIM + c0);
        pf1 = *(const short8v*)(syb + (size_t)(128 * (k + 1) + r1) * DIM + c1);
      }
      const int jt = 2 * k + ts;
      float4v accv[4];
#pragma unroll
      for (int tj = 0; tj < 4; tj++) {
        short8v b0 = *(const short8v*)&ys[ts][(tj * 16 + m) * LSTRIDE + q * 8];
        short8v b1 = *(const short8v*)&ys[ts][(tj * 16 + m) * LSTRIDE + 32 + q * 8];
        float4v c = {0.f, 0.f, 0.f, 0.f};
        c = __builtin_amdgcn_mfma_f32_16x16x32_bf16(a0, b0, c, 0, 0, 0);
        c = __builtin_amdgcn_mfma_f32_16x16x32_bf16(a1, b1, c, 0, 0, 0);
        accv[tj] = c;
      }
#pragma unroll
      for (int tj = 0; tj < 4; tj++) {
        float y2v = y2[(size_t)batch * NPTS + jt * 64 + tj * 16 + m];
#pragma unroll
        for (int reg = 0; reg < 4; reg++) {
          float C = xa[reg] + y2v - 2.0f * accv[tj][reg];
          _Float16 kv = (_Float16)__expf(-INV_EPS * C);
          os[ts][(sw * 16 + q * 4 + reg) * LSTRIDE + tj * 16 + m] = *(const short*)&kv;
        }
      }
      __syncthreads();  // os (cols [k*128,+128)) visible; ys(k) consumed
      // kA grab: wave needs cols [ts*512,+512) == k-steps [ts*4, ts*4+4)
      if ((k >> 2) == ts) {
        int base = (k & 3) * 4;
#pragma unroll
        for (int p = 0; p < 4; p++) {
          int c = p * 32 + q * 8;  // col within this 128-step
          kA[base + p] =
              *(const h8*)&os[c >> 6][(sw * 16 + m) * LSTRIDE + (c & 63)];
        }
      }
      // kB grab: wave k owns cols [k*128,+128); strided col-major reads
      if (k == wave) {
#pragma unroll
        for (int tl = 0; tl < 8; tl++) {
          int c = tl * 16 + m;  // col within this 128-step
          const _Float16* bp =
              (const _Float16*)&os[c >> 6][(q * 8) * LSTRIDE + (c & 63)];
          const _Float16* bp1 =
              (const _Float16*)&os[c >> 6][(32 + q * 8) * LSTRIDE + (c & 63)];
          h8 f0, f1;
#pragma unroll
          for (int e = 0; e < 8; e++) {
            f0[e] = bp[e * LSTRIDE];
            f1[e] = bp1[e * LSTRIDE];
          }
          kB[2 * tl] = f0;
          kB[2 * tl + 1] = f1;
        }
      }
      if (k < 7) {  // ys(k) consumed above the barrier -> safe to overwrite
        *(short8v*)&ys[r0 >> 6][(r0 & 63) * LSTRIDE + c0] = pf0;
        *(short8v*)&ys[r1 >> 6][(r1 & 63) * LSTRIDE + c1] = pf1;
      }
      __syncthreads();  // ys(k+1) visible; os consumed before next overwrite
    }
  }

  for (int j = t; j < NPTS; j += 512) {
    wLDS[j] = 1.f;
    whL[j] = (_Float16)1.f;
  }
  if (t < 64) euL[t] = 1.f;
  __syncthreads();

  float euPrevR = 1.f;  // per-row prev (threads t<64), for the stop-undo
  float eblkR = 0.f;    // block delta (thread 0's wave computes it)
  bool undo = false;
  int it = 0;

  while (true) {
    // ---- Phase A.1: row dots via MFMA (all waves) ----
    {
      float4v Cd = {0.f, 0.f, 0.f, 0.f};
#pragma unroll
      for (int s = 0; s < 16; s++) {
        // w-frag: value depends only on q -> broadcast over the 16 m-lanes
        h8 wf = *(const h8*)&whL[(ts * 16 + s) * 32 + q * 8];
        Cd = __builtin_amdgcn_mfma_f32_16x16x32_f16(kA[s], wf, Cd, 0, 0, 0);
      }
      if (m == 0) {
#pragma unroll
        for (int reg = 0; reg < 4; reg++)
          dotL[ts][sw * 16 + q * 4 + reg] = Cd[reg];
      }
    }
    __syncthreads();  // A1: dotL visible
    // ---- Phase A.2: u-update, one row per thread (wave 0 only) ----
    {
      float dl = 0.f;
      if (t < 64) {
        float dot = dotL[0][t] + dotL[1][t];
        float old = euL[t];
        euPrevR = old;
        float sp = old * dot + 1e-6f;
        float lg = __logf(sp);
        dl = fabsf(EPSF * (log_mu - lg));  // == |u_new - u_old|
        float ai = mu_c * old * __builtin_amdgcn_rcpf(sp);
        euL[t] = ai;
        ahF[t] = (_Float16)(ai * 1024.0f);  // scaled: keeps fp16 normal
      }
      if (wave == 0) {
        float s = waveSum(dl);
        if (lane == 0) eblkR = s;
      }
    }
    __syncthreads();  // A2: ahF/euL visible
    // ---- Phase A.3: colparts via MFMA + atomics (all waves). Value and
    // address MATCH (cs[col]); stagger = tl issue order rotated by kslot. ----
    float* cs = colsum + ((size_t)(it % 3) * BATCH + batch) * NPTS;
    {
      // a-frag: value depends only on q -> broadcast; A rows all equal a_k
      h8 af0 = *(const h8*)&ahF[q * 8];
      h8 af1 = *(const h8*)&ahF[32 + q * 8];
#pragma unroll
      for (int tl = 0; tl < 8; tl++) {
        int tl2 = (tl + kslot) & 7;  // rotate burst order across blocks
        float4v Cc = {0.f, 0.f, 0.f, 0.f};
        Cc = __builtin_amdgcn_mfma_f32_16x16x32_f16(af0, kB[2 * tl2], Cc, 0, 0, 0);
        Cc = __builtin_amdgcn_mfma_f32_16x16x32_f16(af1, kB[2 * tl2 + 1], Cc, 0, 0, 0);
        // Cc[0] = 1024*colpart for col (wave*128 + tl2*16 + m), dup over q/reg
        if (q == 0) unsafeAtomicAdd(&cs[wave * 128 + tl2 * 16 + m], Cc[0]);
      }
    }
    // pre-drain window: lag-1 errB retry overlaps the atomic ack
    if (it >= 1 && t < BATCH) {
      float v;
      while ((v = ATOMIC_LD(&errB[(it - 1) * BATCH + t])) < 0.f) {}
      errbL[t] = v;
    }
    __syncthreads();  // S2: vmcnt drain (atomics at L3) + errbL visible
    if (t == 0)
      ATOMIC_ST(&flags[batch * 16 + kslot],
                ((long long)(it + 2) << 32) | (long long)__float_as_uint(eblkR));
    // ---- lag-1 global stop check (err of previous iteration) ----
    if (it >= 1) {
      float errv = 0.f;
#pragma unroll
      for (int k = 0; k < BATCH; k++) errv += errbL[k];
      if (errv * (1.0f / (float)BATCH) < THRESHF) {
        undo = true;  // reference stopped after body it-1: undo u update
        break;
      }
    }
    // poll peers' flags; the same word carries their deltas
    float dpoll = 0.f;
    if (t < 16) {
      long long fw;
      while ((int)((fw = ATOMIC_LD(&flags[batch * 16 + t])) >> 32) < it + 2) {}
      dpoll = __uint_as_float((unsigned)fw);
    }
    __syncthreads();  // S3: all threads past poll
    // column-sum loads first (critical path; values final per flags)
    float cs0 = ATOMIC_LD(&cs[t]);
    float cs1 = ATOMIC_LD(&cs[t + 512]);
    // zero the buffer for iteration it+2 (race-free: peers' it-1 reads done
    // before they flagged it+2; first adds to it occur after it+2's poll)
    if (t < 64)
      ATOMIC_ST(&colsum[((size_t)((it + 2) % 3) * BATCH + batch) * NPTS +
                        kslot * 64 + t], 0.f);
    // batch err for iteration it: shfl-reduce the 16 polled deltas (wave 0);
    // kslot==0 leader publishes for the cross-batch lag-1 check.
    if (wave == 0) {
      float e16 = (lane < 16) ? dpoll : 0.f;
#pragma unroll
      for (int off = 8; off; off >>= 1) e16 += __shfl_xor(e16, off, 16);
      if (t == 0 && kslot == 0) ATOMIC_ST(&errB[it * BATCH + batch], e16);
    }
    // ---- Phase B: w update, multiplicative, 1024-scale folded bit-exactly:
    // mu*w*rcp(w*cs' + 1e-6*1024)*1024 == mu*w*rcp(w*(cs'/1024) + 1e-6) ----
    {
      float w0 = wLDS[t];
      float wn0 = mu_c * w0 *
                  __builtin_amdgcn_rcpf(w0 * cs0 + (1e-6f * 1024.0f)) * 1024.0f;
      wLDS[t] = wn0;
      whL[t] = (_Float16)wn0;
      float w1 = wLDS[t + 512];
      float wn1 = mu_c * w1 *
                  __builtin_amdgcn_rcpf(w1 * cs1 + (1e-6f * 1024.0f)) * 1024.0f;
      wLDS[t + 512] = wn1;
      whL[t + 512] = (_Float16)wn1;
    }
    it++;
    if (it >= MAX_ITER) break;
    __syncthreads();  // S4: wLDS/whL writes visible before next phase A reads
  }

  // ---- Final cost: pi = a_i*K*w_j, C = -eps*log(K) ----
  {
    if (undo && t < 64) euL[t] = euPrevR;  // restore eu of iteration it-1
    __syncthreads();
    float ai = euL[sw * 16 + m];  // a for this lane's kA rows
    float csum = 0.f;
#pragma unroll
    for (int s = 0; s < 16; s++) {
      int cb = (ts * 16 + s) * 32 + q * 8;
      float4 w0 = *(const float4*)&wLDS[cb];
      float4 w1 = *(const float4*)&wLDS[cb + 4];
      float wv[8] = {w0.x, w0.y, w0.z, w0.w, w1.x, w1.y, w1.z, w1.w};
#pragma unroll
      for (int e = 0; e < 8; e++) {
        float kf = (float)kA[s][e];
        if (kf > 0.f) csum += ai * wv[e] * kf * (-EPSF * __logf(kf));
      }
    }
    csum = waveSum(csum);
    if (lane == 0) derr[wave] = csum;
    __syncthreads();
    if (t == 0) {
      float cst = 0.f;
#pragma unroll
      for (int w = 0; w < 8; w++) cst += derr[w];
      ATOMIC_ST(&costPart[blk], cst + 1.0f);  // bias: sentinel-safe vs poison
    }
    // block 0 gathers all 256 partials and writes the scalar output
    if (blk == 0) {
      float* gb = (float*)&ys[0][0];
      if (t < 256) {
        float v;
        while ((v = ATOMIC_LD(&costPart[t])) < 0.5f) {}
        gb[t] = v;
      }
      __syncthreads();
      if (wave == 0) {
        float s = gb[lane] + gb[lane + 64] + gb[lane + 128] + gb[lane + 192];
        s = waveSum(s);
        if (lane == 0) out[0] = (s - 256.0f) * (1.0f / (float)BATCH);
      }
    }
  }
}

extern "C" void kernel_launch(void* const* d_in, const int* in_sizes, int n_in,
                              void* d_out, int out_size, void* d_ws,
                              size_t ws_size, hipStream_t stream) {
  (void)in_sizes; (void)n_in; (void)out_size; (void)ws_size;
  const float* x = (const float*)d_in[0];
  const float* y = (const float*)d_in[1];
  float* out = (float*)d_out;

  char* ws = (char*)d_ws;
  size_t off = 0;
  auto alloc = [&](size_t nbytes) -> void* {
    void* p = (void*)(ws + off);
    off = (off + nbytes + 255) & ~(size_t)255;
    return p;
  };
  __hip_bfloat16* syh = (__hip_bfloat16*)alloc((size_t)BATCH * NPTS * DIM * 2);
  float* y2 = (float*)alloc((size_t)BATCH * NPTS * 4);
  float* colsum = (float*)alloc((size_t)3 * BATCH * NPTS * 4);
  long long* flags = (long long*)alloc((size_t)BATCH * 16 * 8);
  float* errB = (float*)alloc((size_t)MAX_ITER * BATCH * 4);
  float* costPart = (float*)alloc(256 * 4);

  void* args[] = {&x, &y, &syh, &y2, &colsum, &flags,
                  &errB, &costPart, &out};
  hipLaunchCooperativeKernel((void*)sinkhorn_fused, dim3(256), dim3(512), args,
                             0, stream);
}

// Round 12
// 122.304 us; speedup vs baseline: 1.2096x; 1.1664x over previous
//
#include <hip/hip_runtime.h>
#include <hip/hip_bf16.h>
#include <math.h>

#define BATCH 16
#define NPTS 1024
#define DIM 64
#define EPSF 0.1f
#define INV_EPS 10.0f
#define MAX_ITER 100
#define THRESHF 0.1f
#define LSTRIDE 72  // shorts; 64+8 pad keeps b128 LDS reads conflict-cheap

typedef _Float16 h8 __attribute__((ext_vector_type(8)));
typedef short short8v __attribute__((ext_vector_type(8)));
typedef float float4v __attribute__((ext_vector_type(4)));

#define ATOMIC_ST(p, v) \
  __hip_atomic_store((p), (v), __ATOMIC_RELAXED, __HIP_MEMORY_SCOPE_AGENT)
#define ATOMIC_LD(p) \
  __hip_atomic_load((p), __ATOMIC_RELAXED, __HIP_MEMORY_SCOPE_AGENT)

__device__ inline float waveSum(float x) {
#pragma unroll
  for (int off = 32; off; off >>= 1) x += __shfl_xor(x, off, 64);
  return x;
}
__device__ inline float waveMax(float x) {
#pragma unroll
  for (int off = 32; off; off >>= 1) x = fmaxf(x, __shfl_xor(x, off, 64));
  return x;
}

// Single fused cooperative kernel. 256 blocks x 512 threads, 1 block/CU.
// Block owns rows [kslot*64,+64) of batch (blk&7)+8*(blk>>7).
//
// Round-12 = round-11 (correctness verified on HW, absmax 0.0) with the
// rule-#20 violation fixed: round-11 indexed kB[2*tl2] with runtime
// tl2=(tl+kslot)&7 -> the 64-VGPR kB array went to SCRATCH (VGPR_Count 80,
// 70MB/dispatch spill traffic, 51.5->70.7us). The burst rotation is
// deleted; all register-array indices are compile-time constants again.
//
// Round-8 exchange protocol (best measured, bit-identical) with Phase A
// on MFMA (vector-pipe matvecs were 29% VALUBusy, MfmaUtil 1.4%):
//  - K resident TWICE per wave, in the two mfma operand layouts (verified
//    by round-11's passing run):
//      kA[16]: A-layout, rows [sw*16,+16) x cols [ts*512,+512)
//              (sw=wave&3, ts=wave>>2; lane m=lane&15 row, q=lane>>4 k-grp)
//      kB[16]: B-layout, all 64 rows x cols [wave*128,+128)
//  - row dots: 16 mfma_f32_16x16x32_f16(kA[s], w-frag bcast) -> C[reg] =
//    dot(row sw*16+q*4+reg) dup over m; m==0 lanes -> dotL.
//  - u-update: threads t<64 (1 row each), eu in LDS (euL), a*1024 -> ahF
//    fp16 (same x1024 scaling as rounds 5/8, folds bit-exactly in Phase B).
//  - colparts: mfma(a-frag bcast, kB) -> C[0] = colpart(col) dup; q==0
//    lanes issue the f32 atomicAdds at cs[col] (value/address matched).
//    The colpart LDS exchange (32KB + its barrier traffic) is deleted.
// Exchange: atomicAdd colsum[3] triple-buffer, 64-bit flags tag<<32|delta,
// lag-1 errB stop — unchanged from round 8.
// Poison-compat (0xAA): flag tag high-word signed (poison<1), errB "<0"
// sentinel, costPart +1.0 bias "<0.5" sentinel, colsum zeroed in prologue.
__global__ __launch_bounds__(512, 2) void sinkhorn_fused(
    const float* __restrict__ x, const float* __restrict__ y,
    __hip_bfloat16* __restrict__ syh,  // [BATCH*NPTS*DIM] bf16
    float* __restrict__ y2,            // [BATCH*NPTS]
    float* __restrict__ colsum,        // [3][BATCH][NPTS] (scaled x1024)
    long long* __restrict__ flags,     // [BATCH][16]: tag<<32 | delta bits
    float* __restrict__ errB,          // [MAX_ITER][BATCH], sentinel <0
    float* __restrict__ costPart,      // [256], sentinel <0.5
    float* __restrict__ out) {
  __shared__ __attribute__((aligned(16))) short xs[64 * LSTRIDE];
  __shared__ __attribute__((aligned(16))) short ys[2][64 * LSTRIDE];
  __shared__ __attribute__((aligned(16))) short os[2][64 * LSTRIDE];
  __shared__ __attribute__((aligned(16))) float wLDS[NPTS];
  __shared__ __attribute__((aligned(16))) _Float16 whL[NPTS];
  __shared__ __attribute__((aligned(16))) _Float16 ahF[64];  // a*1024 fp16
  __shared__ __attribute__((aligned(16))) float dotL[2][64];
  __shared__ __attribute__((aligned(16))) float euL[64];
  __shared__ float x2L[64];
  __shared__ float derr[8];
  __shared__ float errbL[BATCH];
  const int t = threadIdx.x;
  const int blk = blockIdx.x;
  const int wave = t >> 6, lane = t & 63;
  const int batch = (blk & 7) + 8 * (blk >> 7);
  const int kslot = (blk >> 3) & 15;
  const float log_mu = logf(1.0f / 1024.0f + 1e-8f);
  const float mu_c = 1.0f / 1024.0f + 1e-8f;  // exp(log_mu)

  // ---- Phase 0: softmax. x-rows -> LDS only; y-rows -> global via L3. ----
#pragma unroll
  for (int rr = 0; rr < 8; rr++) {
    int rl = wave * 8 + rr;  // 0..63 local row
    int gr = batch * NPTS + kslot * 64 + rl;
    float xv = x[(size_t)gr * DIM + lane];
    float mx = waveMax(xv);
    float ex = __expf(xv - mx);
    float sx = waveSum(ex);
    float px = ex / sx;
    __hip_bfloat16 hbx = (__hip_bfloat16)px;
    xs[rl * LSTRIDE + lane] = *(const short*)&hbx;
    float sqx = waveSum(px * px);
    if (lane == 0) x2L[rl] = sqx;
    float yv = y[(size_t)gr * DIM + lane];
    float my = waveMax(yv);
    float ey = __expf(yv - my);
    float sy = waveSum(ey);
    float py = ey / sy;
    __hip_bfloat16 hby = (__hip_bfloat16)py;
    unsigned bits = *(const unsigned short*)&hby;
    unsigned nb = __shfl_down(bits, 1);
    if ((lane & 1) == 0)
      ATOMIC_ST((unsigned*)((unsigned short*)syh + (size_t)gr * DIM + lane),
                bits | (nb << 16));
    float sqy = waveSum(py * py);
    if (lane == 0) ATOMIC_ST(&y2[gr], sqy);
  }
  // zero own colsum slices of all 3 buffers (before any peer can add)
  if (t < 192) {
    int buf = t >> 6, j = kslot * 64 + (t & 63);
    ATOMIC_ST(&colsum[((size_t)buf * BATCH + batch) * NPTS + j], 0.f);
  }
  __syncthreads();  // vmcnt drain: all publishes complete at L3
  if (t == 0) ATOMIC_ST(&flags[batch * 16 + kslot], (long long)1 << 32);
  if (t < 16) {
    while ((int)(ATOMIC_LD(&flags[batch * 16 + t]) >> 32) < 1) {}
  }
  __syncthreads();

  // ---- Prologue: build K slab via MFMA; grab kA (A-layout) + kB (B-layout)
  // from the os tiles. T14 prefetch of next stage spans the compute. ----
  const int m = lane & 15, q = lane >> 4;
  const int sw = wave & 3, ts = wave >> 2;
  short8v a0 = *(const short8v*)&xs[(sw * 16 + m) * LSTRIDE + q * 8];
  short8v a1 = *(const short8v*)&xs[(sw * 16 + m) * LSTRIDE + 32 + q * 8];
  float xa[4];
#pragma unroll
  for (int reg = 0; reg < 4; reg++) xa[reg] = x2L[sw * 16 + q * 4 + reg];
  h8 kA[16];  // rows [sw*16,+16) x cols [ts*512,+512): frag s -> cols s*32
  h8 kB[16];  // all 64 rows x cols [wave*128,+128): frag 2*tl+h
  {
    const int r0 = t >> 3, c0 = (t & 7) * 8;
    const int r1 = (t + 512) >> 3, c1 = ((t + 512) & 7) * 8;
    const short* syb = (const short*)syh + (size_t)batch * NPTS * DIM;
    short8v pf0 = *(const short8v*)(syb + (size_t)r0 * DIM + c0);
    short8v pf1 = *(const short8v*)(syb + (size_t)r1 * DIM + c1);
    *(short8v*)&ys[r0 >> 6][(r0 & 63) * LSTRIDE + c0] = pf0;
    *(short8v*)&ys[r1 >> 6][(r1 & 63) * LSTRIDE + c1] = pf1;
    __syncthreads();  // stage 0 visible
#pragma unroll
    for (int k = 0; k < 8; k++) {
      if (k < 7) {  // issue next-stage loads; flight hides under MFMA+expf
        pf0 = *(const short8v*)(syb + (size_t)(128 * (k + 1) + r0) * DIM + c0);
        pf1 = *(const short8v*)(syb + (size_t)(128 * (k + 1) + r1) * DIM + c1);
      }
      const int jt = 2 * k + ts;
      float4v accv[4];
#pragma unroll
      for (int tj = 0; tj < 4; tj++) {
        short8v b0 = *(const short8v*)&ys[ts][(tj * 16 + m) * LSTRIDE + q * 8];
        short8v b1 = *(const short8v*)&ys[ts][(tj * 16 + m) * LSTRIDE + 32 + q * 8];
        float4v c = {0.f, 0.f, 0.f, 0.f};
        c = __builtin_amdgcn_mfma_f32_16x16x32_bf16(a0, b0, c, 0, 0, 0);
        c = __builtin_amdgcn_mfma_f32_16x16x32_bf16(a1, b1, c, 0, 0, 0);
        accv[tj] = c;
      }
#pragma unroll
      for (int tj = 0; tj < 4; tj++) {
        float y2v = y2[(size_t)batch * NPTS + jt * 64 + tj * 16 + m];
#pragma unroll
        for (int reg = 0; reg < 4; reg++) {
          float C = xa[reg] + y2v - 2.0f * accv[tj][reg];
          _Float16 kv = (_Float16)__expf(-INV_EPS * C);
          os[ts][(sw * 16 + q * 4 + reg) * LSTRIDE + tj * 16 + m] = *(const short*)&kv;
        }
      }
      __syncthreads();  // os (cols [k*128,+128)) visible; ys(k) consumed
      // kA grab: wave needs cols [ts*512,+512) == k-steps [ts*4, ts*4+4)
      if ((k >> 2) == ts) {
        int base = (k & 3) * 4;
#pragma unroll
        for (int p = 0; p < 4; p++) {
          int c = p * 32 + q * 8;  // col within this 128-step
          kA[base + p] =
              *(const h8*)&os[c >> 6][(sw * 16 + m) * LSTRIDE + (c & 63)];
        }
      }
      // kB grab: wave k owns cols [k*128,+128); strided col-major reads
      if (k == wave) {
#pragma unroll
        for (int tl = 0; tl < 8; tl++) {
          int c = tl * 16 + m;  // col within this 128-step
          const _Float16* bp =
              (const _Float16*)&os[c >> 6][(q * 8) * LSTRIDE + (c & 63)];
          const _Float16* bp1 =
              (const _Float16*)&os[c >> 6][(32 + q * 8) * LSTRIDE + (c & 63)];
          h8 f0, f1;
#pragma unroll
          for (int e = 0; e < 8; e++) {
            f0[e] = bp[e * LSTRIDE];
            f1[e] = bp1[e * LSTRIDE];
          }
          kB[2 * tl] = f0;
          kB[2 * tl + 1] = f1;
        }
      }
      if (k < 7) {  // ys(k) consumed above the barrier -> safe to overwrite
        *(short8v*)&ys[r0 >> 6][(r0 & 63) * LSTRIDE + c0] = pf0;
        *(short8v*)&ys[r1 >> 6][(r1 & 63) * LSTRIDE + c1] = pf1;
      }
      __syncthreads();  // ys(k+1) visible; os consumed before next overwrite
    }
  }

  for (int j = t; j < NPTS; j += 512) {
    wLDS[j] = 1.f;
    whL[j] = (_Float16)1.f;
  }
  if (t < 64) euL[t] = 1.f;
  __syncthreads();

  float euPrevR = 1.f;  // per-row prev (threads t<64), for the stop-undo
  float eblkR = 0.f;    // block delta (thread 0's wave computes it)
  bool undo = false;
  int it = 0;

  while (true) {
    // ---- Phase A.1: row dots via MFMA (all waves) ----
    {
      float4v Cd = {0.f, 0.f, 0.f, 0.f};
#pragma unroll
      for (int s = 0; s < 16; s++) {
        // w-frag: value depends only on q -> broadcast over the 16 m-lanes
        h8 wf = *(const h8*)&whL[(ts * 16 + s) * 32 + q * 8];
        Cd = __builtin_amdgcn_mfma_f32_16x16x32_f16(kA[s], wf, Cd, 0, 0, 0);
      }
      if (m == 0) {
#pragma unroll
        for (int reg = 0; reg < 4; reg++)
          dotL[ts][sw * 16 + q * 4 + reg] = Cd[reg];
      }
    }
    __syncthreads();  // A1: dotL visible
    // ---- Phase A.2: u-update, one row per thread (wave 0 only) ----
    {
      float dl = 0.f;
      if (t < 64) {
        float dot = dotL[0][t] + dotL[1][t];
        float old = euL[t];
        euPrevR = old;
        float sp = old * dot + 1e-6f;
        float lg = __logf(sp);
        dl = fabsf(EPSF * (log_mu - lg));  // == |u_new - u_old|
        float ai = mu_c * old * __builtin_amdgcn_rcpf(sp);
        euL[t] = ai;
        ahF[t] = (_Float16)(ai * 1024.0f);  // scaled: keeps fp16 normal
      }
      if (wave == 0) {
        float s = waveSum(dl);
        if (lane == 0) eblkR = s;
      }
    }
    __syncthreads();  // A2: ahF/euL visible
    // ---- Phase A.3: colparts via MFMA + atomics (all waves). Static tl
    // indices only (rule #20); value/address matched at cs[col]. ----
    float* cs = colsum + ((size_t)(it % 3) * BATCH + batch) * NPTS;
    {
      // a-frag: value depends only on q -> broadcast; A rows all equal a_k
      h8 af0 = *(const h8*)&ahF[q * 8];
      h8 af1 = *(const h8*)&ahF[32 + q * 8];
#pragma unroll
      for (int tl = 0; tl < 8; tl++) {
        float4v Cc = {0.f, 0.f, 0.f, 0.f};
        Cc = __builtin_amdgcn_mfma_f32_16x16x32_f16(af0, kB[2 * tl], Cc, 0, 0, 0);
        Cc = __builtin_amdgcn_mfma_f32_16x16x32_f16(af1, kB[2 * tl + 1], Cc, 0, 0, 0);
        // Cc[0] = 1024*colpart for col (wave*128 + tl*16 + m), dup over q/reg
        if (q == 0) unsafeAtomicAdd(&cs[wave * 128 + tl * 16 + m], Cc[0]);
      }
    }
    // pre-drain window: lag-1 errB retry overlaps the atomic ack
    if (it >= 1 && t < BATCH) {
      float v;
      while ((v = ATOMIC_LD(&errB[(it - 1) * BATCH + t])) < 0.f) {}
      errbL[t] = v;
    }
    __syncthreads();  // S2: vmcnt drain (atomics at L3) + errbL visible
    if (t == 0)
      ATOMIC_ST(&flags[batch * 16 + kslot],
                ((long long)(it + 2) << 32) | (long long)__float_as_uint(eblkR));
    // ---- lag-1 global stop check (err of previous iteration) ----
    if (it >= 1) {
      float errv = 0.f;
#pragma unroll
      for (int k = 0; k < BATCH; k++) errv += errbL[k];
      if (errv * (1.0f / (float)BATCH) < THRESHF) {
        undo = true;  // reference stopped after body it-1: undo u update
        break;
      }
    }
    // poll peers' flags; the same word carries their deltas
    float dpoll = 0.f;
    if (t < 16) {
      long long fw;
      while ((int)((fw = ATOMIC_LD(&flags[batch * 16 + t])) >> 32) < it + 2) {}
      dpoll = __uint_as_float((unsigned)fw);
    }
    __syncthreads();  // S3: all threads past poll
    // column-sum loads first (critical path; values final per flags)
    float cs0 = ATOMIC_LD(&cs[t]);
    float cs1 = ATOMIC_LD(&cs[t + 512]);
    // zero the buffer for iteration it+2 (race-free: peers' it-1 reads done
    // before they flagged it+2; first adds to it occur after it+2's poll)
    if (t < 64)
      ATOMIC_ST(&colsum[((size_t)((it + 2) % 3) * BATCH + batch) * NPTS +
                        kslot * 64 + t], 0.f);
    // batch err for iteration it: shfl-reduce the 16 polled deltas (wave 0);
    // kslot==0 leader publishes for the cross-batch lag-1 check.
    if (wave == 0) {
      float e16 = (lane < 16) ? dpoll : 0.f;
#pragma unroll
      for (int off = 8; off; off >>= 1) e16 += __shfl_xor(e16, off, 16);
      if (t == 0 && kslot == 0) ATOMIC_ST(&errB[it * BATCH + batch], e16);
    }
    // ---- Phase B: w update, multiplicative, 1024-scale folded bit-exactly:
    // mu*w*rcp(w*cs' + 1e-6*1024)*1024 == mu*w*rcp(w*(cs'/1024) + 1e-6) ----
    {
      float w0 = wLDS[t];
      float wn0 = mu_c * w0 *
                  __builtin_amdgcn_rcpf(w0 * cs0 + (1e-6f * 1024.0f)) * 1024.0f;
      wLDS[t] = wn0;
      whL[t] = (_Float16)wn0;
      float w1 = wLDS[t + 512];
      float wn1 = mu_c * w1 *
                  __builtin_amdgcn_rcpf(w1 * cs1 + (1e-6f * 1024.0f)) * 1024.0f;
      wLDS[t + 512] = wn1;
      whL[t + 512] = (_Float16)wn1;
    }
    it++;
    if (it >= MAX_ITER) break;
    __syncthreads();  // S4: wLDS/whL writes visible before next phase A reads
  }

  // ---- Final cost: pi = a_i*K*w_j, C = -eps*log(K) ----
  {
    if (undo && t < 64) euL[t] = euPrevR;  // restore eu of iteration it-1
    __syncthreads();
    float ai = euL[sw * 16 + m];  // a for this lane's kA rows
    float csum = 0.f;
#pragma unroll
    for (int s = 0; s < 16; s++) {
      int cb = (ts * 16 + s) * 32 + q * 8;
      float4 w0 = *(const float4*)&wLDS[cb];
      float4 w1 = *(const float4*)&wLDS[cb + 4];
      float wv[8] = {w0.x, w0.y, w0.z, w0.w, w1.x, w1.y, w1.z, w1.w};
#pragma unroll
      for (int e = 0; e < 8; e++) {
        float kf = (float)kA[s][e];
        if (kf > 0.f) csum += ai * wv[e] * kf * (-EPSF * __logf(kf));
      }
    }
    csum = waveSum(csum);
    if (lane == 0) derr[wave] = csum;
    __syncthreads();
    if (t == 0) {
      float cst = 0.f;
#pragma unroll
      for (int w = 0; w < 8; w++) cst += derr[w];
      ATOMIC_ST(&costPart[blk], cst + 1.0f);  // bias: sentinel-safe vs poison
    }
    // block 0 gathers all 256 partials and writes the scalar output
    if (blk == 0) {
      float* gb = (float*)&ys[0][0];
      if (t < 256) {
        float v;
        while ((v = ATOMIC_LD(&costPart[t])) < 0.5f) {}
        gb[t] = v;
      }
      __syncthreads();
      if (wave == 0) {
        float s = gb[lane] + gb[lane + 64] + gb[lane + 128] + gb[lane + 192];
        s = waveSum(s);
        if (lane == 0) out[0] = (s - 256.0f) * (1.0f / (float)BATCH);
      }
    }
  }
}

extern "C" void kernel_launch(void* const* d_in, const int* in_sizes, int n_in,
                              void* d_out, int out_size, void* d_ws,
                              size_t ws_size, hipStream_t stream) {
  (void)in_sizes; (void)n_in; (void)out_size; (void)ws_size;
  const float* x = (const float*)d_in[0];
  const float* y = (const float*)d_in[1];
  float* out = (float*)d_out;

  char* ws = (char*)d_ws;
  size_t off = 0;
  auto alloc = [&](size_t nbytes) -> void* {
    void* p = (void*)(ws + off);
    off = (off + nbytes + 255) & ~(size_t)255;
    return p;
  };
  __hip_bfloat16* syh = (__hip_bfloat16*)alloc((size_t)BATCH * NPTS * DIM * 2);
  float* y2 = (float*)alloc((size_t)BATCH * NPTS * 4);
  float* colsum = (float*)alloc((size_t)3 * BATCH * NPTS * 4);
  long long* flags = (long long*)alloc((size_t)BATCH * 16 * 8);
  float* errB = (float*)alloc((size_t)MAX_ITER * BATCH * 4);
  float* costPart = (float*)alloc(256 * 4);

  void* args[] = {&x, &y, &syh, &y2, &colsum, &flags,
                  &errB, &costPart, &out};
  hipLaunchCooperativeKernel((void*)sinkhorn_fused, dim3(256), dim3(512), args,
                             0, stream);
}